// Round 6
// baseline (890.775 us; speedup 1.0000x reference)
//
#include <hip/hip_runtime.h>

#define N_NODES 50000
#define N_EDGES 800000
// dims: IN=HID=256, OUT=2

static inline int cdiv(int a, int b) { return (a + b - 1) / b; }

typedef __attribute__((ext_vector_type(8))) short bf16x8;
typedef __attribute__((ext_vector_type(4))) float f32x4;
typedef __attribute__((ext_vector_type(2))) float f32x2;
typedef __attribute__((ext_vector_type(4))) unsigned int u32x4;

static __device__ __forceinline__ unsigned short f2bf(float f) {
    unsigned int u = __float_as_uint(f);
    unsigned int r = (u + 0x7FFF + ((u >> 16) & 1)) >> 16;  // RNE
    return (unsigned short)r;
}
static __device__ __forceinline__ float bf2f(unsigned short h) {
    return __uint_as_float((unsigned int)h << 16);
}
static __device__ __forceinline__ float bf_lo(unsigned int u) { return __uint_as_float(u << 16); }
static __device__ __forceinline__ float bf_hi(unsigned int u) { return __uint_as_float(u & 0xFFFF0000u); }

// nontemporal 8B load of an edge record (streamed once; keep L2 for the gather)
static __device__ __forceinline__ int2 ldnt2(const int2* p) {
    unsigned long long u = __builtin_nontemporal_load((const unsigned long long*)p);
    int2 r;
    r.x = (int)(u & 0xFFFFFFFFull);
    r.y = (int)(u >> 32);
    return r;
}

// accumulate 8 bf16 lanes of v (uint4) scaled by wgt into acc2[0..3] (float2 pairs)
static __device__ __forceinline__ void acc8p(f32x2* acc, uint4 v, float wgt) {
    f32x2 w2;
    w2.x = wgt;
    w2.y = wgt;
    f32x2 p;
    p.x = bf_lo(v.x); p.y = bf_hi(v.x); acc[0] += p * w2;
    p.x = bf_lo(v.y); p.y = bf_hi(v.y); acc[1] += p * w2;
    p.x = bf_lo(v.z); p.y = bf_hi(v.z); acc[2] += p * w2;
    p.x = bf_lo(v.w); p.y = bf_hi(v.w); acc[3] += p * w2;
}

// ---------------- CSR build ----------------

__global__ void k_count(const int* __restrict__ edst, int* cnt, int e) {
    int i = (blockIdx.x * 256 + threadIdx.x) * 4;
    if (i + 3 < e) {
        int4 v = *(const int4*)(edst + i);
        atomicAdd(&cnt[v.x], 1);
        atomicAdd(&cnt[v.y], 1);
        atomicAdd(&cnt[v.z], 1);
        atomicAdd(&cnt[v.w], 1);
    } else {
        for (int k = i; k < e; ++k) atomicAdd(&cnt[edst[k]], 1);
    }
}

__global__ __launch_bounds__(256) void k_scan1(const int* __restrict__ cnt,
                                               int* __restrict__ row_ptr,
                                               float* __restrict__ dis,
                                               int* __restrict__ blk, int n) {
    __shared__ int sums[256];
    int t = threadIdx.x;
    int base = blockIdx.x * 1024 + t * 4;
    int c0 = 0, c1 = 0, c2 = 0, c3 = 0;
    if (base + 3 < n) {
        int4 v = *(const int4*)(cnt + base);
        c0 = v.x + 1; c1 = v.y + 1; c2 = v.z + 1; c3 = v.w + 1;  // +1 self-loop
    } else {
        if (base + 0 < n) c0 = cnt[base + 0] + 1;
        if (base + 1 < n) c1 = cnt[base + 1] + 1;
        if (base + 2 < n) c2 = cnt[base + 2] + 1;
        if (base + 3 < n) c3 = cnt[base + 3] + 1;
    }
    int s = c0 + c1 + c2 + c3;
    sums[t] = s;
    __syncthreads();
    int x = s;
    for (int off = 1; off < 256; off <<= 1) {
        int y = (t >= off) ? sums[t - off] : 0;
        __syncthreads();
        x += y;
        sums[t] = x;
        __syncthreads();
    }
    int excl = x - s;
    if (base + 0 < n) { row_ptr[base + 0] = excl;                dis[base + 0] = rsqrtf((float)c0); }
    if (base + 1 < n) { row_ptr[base + 1] = excl + c0;           dis[base + 1] = rsqrtf((float)c1); }
    if (base + 2 < n) { row_ptr[base + 2] = excl + c0 + c1;      dis[base + 2] = rsqrtf((float)c2); }
    if (base + 3 < n) { row_ptr[base + 3] = excl + c0 + c1 + c2; dis[base + 3] = rsqrtf((float)c3); }
    if (t == 255) blk[blockIdx.x] = x;
}

__global__ __launch_bounds__(256) void k_scan2(int* __restrict__ blk,
                                               int* __restrict__ row_ptr_n, int nb) {
    __shared__ int sums[256];
    int t = threadIdx.x;
    int s = (t < nb) ? blk[t] : 0;
    sums[t] = s;
    __syncthreads();
    int x = s;
    for (int off = 1; off < 256; off <<= 1) {
        int y = (t >= off) ? sums[t - off] : 0;
        __syncthreads();
        x += y;
        sums[t] = x;
        __syncthreads();
    }
    if (t < nb) blk[t] = x - s;
    if (t == 255) row_ptr_n[0] = x;
}

__global__ __launch_bounds__(256) void k_scan3(int* __restrict__ row_ptr,
                                               int* __restrict__ pos,
                                               const int* __restrict__ blk, int n) {
    int base = blockIdx.x * 1024 + threadIdx.x * 4;
    int off = blk[blockIdx.x];
#pragma unroll
    for (int i = 0; i < 4; ++i) {
        int idx = base + i;
        if (idx < n) {
            int v = row_ptr[idx] + off;
            row_ptr[idx] = v;
            pos[idx] = v;
        }
    }
}

// merged: items [0,E) = edges, [E, E+N) = self-loops.
__global__ void k_fill(const int* __restrict__ esrc, const int* __restrict__ edst,
                       int* pos, const float* __restrict__ dis,
                       int2* __restrict__ eg, int e, int n) {
    int i = blockIdx.x * 256 + threadIdx.x;
    if (i < e) {
        int s = esrc[i], d = edst[i];
        int p = atomicAdd(&pos[d], 1);
        unsigned long long u = (unsigned long long)(unsigned int)s |
                               ((unsigned long long)(unsigned int)__float_as_int(dis[s] * dis[d]) << 32);
        __builtin_nontemporal_store(u, (unsigned long long*)&eg[p]);
    } else if (i < e + n) {
        int v = i - e;
        int p = atomicAdd(&pos[v], 1);
        float dv = dis[v];
        unsigned long long u = (unsigned long long)(unsigned int)v |
                               ((unsigned long long)(unsigned int)__float_as_int(dv * dv) << 32);
        __builtin_nontemporal_store(u, (unsigned long long*)&eg[p]);
    }
}

// ---------------- prep ----------------
// blocks 0..47: weight split via LDS 64x64 tile transpose (coalesced both sides).
// block 48: bias/W3 permute. blocks 49+: x -> bf16 cast.

__global__ __launch_bounds__(256) void k_prep(const float* __restrict__ W0,
                                              const float* __restrict__ W1,
                                              const float* __restrict__ W2,
                                              const float* __restrict__ b0,
                                              const float* __restrict__ b1,
                                              const float* __restrict__ b2,
                                              const float* __restrict__ W3,
                                              unsigned short* __restrict__ Wth,
                                              unsigned short* __restrict__ Wtl,
                                              float* __restrict__ bpw,
                                              const float* __restrict__ X,
                                              unsigned short* __restrict__ Xh, long total4) {
    if (blockIdx.x < 48) {
        __shared__ float tile[64][65];
        int layer = blockIdx.x / 16;
        int tid = blockIdx.x % 16;
        int ti = tid >> 2, tj = tid & 3;  // ti: k-tile, tj: n-tile
        const float* W = layer == 0 ? W0 : (layer == 1 ? W1 : W2);
        int r0 = ti * 64, n0 = tj * 64;
        int rr = threadIdx.x >> 4;          // 0..15
        int cc = (threadIdx.x & 15) * 4;    // 0..60
#pragma unroll
        for (int j = 0; j < 4; ++j) {
            float4 v = *(const float4*)(W + (size_t)(r0 + rr + j * 16) * 256 + n0 + cc);
            tile[rr + j * 16][cc + 0] = v.x;
            tile[rr + j * 16][cc + 1] = v.y;
            tile[rr + j * 16][cc + 2] = v.z;
            tile[rr + j * 16][cc + 3] = v.w;
        }
        __syncthreads();
        int pl = threadIdx.x & 63;   // p within tile
        int ng = threadIdx.x >> 6;   // 0..3
        int kl = (layer != 0) ? ((pl & 3) * 16 + (pl >> 2)) : pl;  // logc within 64
#pragma unroll
        for (int i = 0; i < 16; ++i) {
            int nl = ng * 16 + i;
            float v = tile[kl][nl];
            unsigned short h = f2bf(v);
            size_t o = (size_t)layer * 65536 + (size_t)(n0 + nl) * 256 + r0 + pl;
            Wth[o] = h;
            Wtl[o] = f2bf(v - bf2f(h));
        }
    } else if (blockIdx.x == 48) {
        int p = threadIdx.x;
        int pl = p & 63;
        int c = (p & ~63) + (pl & 3) * 16 + (pl >> 2);  // logc
        bpw[p] = b0[c];
        bpw[256 + p] = b1[c];
        bpw[512 + p] = b2[c];
        bpw[768 + p * 2 + 0] = W3[(size_t)c * 2 + 0];
        bpw[768 + p * 2 + 1] = W3[(size_t)c * 2 + 1];
    } else {
        long i = (long)(blockIdx.x - 49) * 256 + threadIdx.x;
        if (i >= total4) return;
        float4 v = *(const float4*)(X + i * 4);
        ushort4 h;
        h.x = f2bf(v.x);
        h.y = f2bf(v.y);
        h.z = f2bf(v.z);
        h.w = f2bf(v.w);
        *(ushort4*)(Xh + i * 4) = h;
    }
}

// ---------------- MFMA GEMM: Ah(bf16)[M,256] @ Wsplit -> bf16 [M,256] ----
// NO LDS: both bh and bl read directly from global. Per-colblock weight slices
// (32 KB hi + 32 KB lo) are L2-resident (128 KB weights total per XCD).
// Deletes the stage + barrier; occupancy now VGPR-bound: __launch_bounds__(256,6)
// -> 24 waves/CU (was 16 with the 33.8 KB LDS stage) for A-load latency hiding.
// XCD-pinned dispatch kept: the 4 col-blocks of a row-panel share one XCD's L2.

#define GEMM_RB 196  // cdiv(50000,256)
#define GEMM_GRID (((GEMM_RB + 7) / 8) * 32)  // 8 xcd * 25 q * 4 c = 800

__global__ __launch_bounds__(256, 6) void k_gemm_mfma(const unsigned short* __restrict__ Ah,
                                                      const unsigned short* __restrict__ Wth,
                                                      const unsigned short* __restrict__ Wtl,
                                                      unsigned short* __restrict__ C, int M) {
    int x = blockIdx.x & 7;
    int t5 = blockIdx.x >> 3;
    int q = t5 >> 2, cb = t5 & 3;
    int rowblk = q * 8 + x;
    if (rowblk >= GEMM_RB) return;  // uniform early-exit (dummy blocks)
    int c0 = cb * 64;
    int m0 = rowblk * 256;
    int t = threadIdx.x;

    int lane = t & 63, wave = t >> 6;
    int quad = lane >> 4, l16 = lane & 15;

    const unsigned short* aph[4];
#pragma unroll
    for (int mt = 0; mt < 4; ++mt) {
        int m = m0 + wave * 64 + mt * 16 + l16;
        if (m >= M) m = M - 1;  // clamp loads; stores guarded
        aph[mt] = Ah + (size_t)m * 256 + quad * 8;
    }
    // per-lane bases for direct global weights (hi and lo), L2-hot
    const unsigned short* bhp = Wth + (size_t)(c0 + l16) * 256 + quad * 8;
    const unsigned short* blp = Wtl + (size_t)(c0 + l16) * 256 + quad * 8;

    f32x4 acc[4][4];
#pragma unroll
    for (int i = 0; i < 4; ++i)
#pragma unroll
        for (int j = 0; j < 4; ++j) acc[i][j] = (f32x4){0.f, 0.f, 0.f, 0.f};

#pragma unroll 2
    for (int kc = 0; kc < 8; ++kc) {
        int ko = kc * 32;
        bf16x8 ahf[4];
#pragma unroll
        for (int mt = 0; mt < 4; ++mt) ahf[mt] = *(const bf16x8*)(aph[mt] + ko);
#pragma unroll
        for (int nt = 0; nt < 4; ++nt) {
            bf16x8 bh = *(const bf16x8*)(bhp + nt * 16 * 256 + ko);
            bf16x8 bl = *(const bf16x8*)(blp + nt * 16 * 256 + ko);
#pragma unroll
            for (int mt = 0; mt < 4; ++mt) {
                acc[mt][nt] = __builtin_amdgcn_mfma_f32_16x16x32_bf16(ahf[mt], bh, acc[mt][nt], 0, 0, 0);
                acc[mt][nt] = __builtin_amdgcn_mfma_f32_16x16x32_bf16(ahf[mt], bl, acc[mt][nt], 0, 0, 0);
            }
        }
    }

    // permuted store: per (mt,r) one ushort4 at phys cols c0 + l16*4 + {0..3}
#pragma unroll
    for (int mt = 0; mt < 4; ++mt) {
#pragma unroll
        for (int r = 0; r < 4; ++r) {
            int row = m0 + wave * 64 + mt * 16 + quad * 4 + r;
            if (row < M) {
                ushort4 sv;
                sv.x = f2bf(acc[mt][0][r]);
                sv.y = f2bf(acc[mt][1][r]);
                sv.z = f2bf(acc[mt][2][r]);
                sv.w = f2bf(acc[mt][3][r]);
                *(ushort4*)(C + (size_t)row * 256 + c0 + l16 * 4) = sv;
            }
        }
    }
}

// ---------------- aggregation dim=256 over (permuted) bf16 messages ----------------
// one block per 4 nodes, in-dispatch-order (preserves gather L2 locality —
// measured R1 vs R2). wave per node, half-wave per edge, 6 edges in flight.
// MODE 0: bias+relu -> bf16 store. MODE 1: fused [256,2] projection -> t2.

template <int MODE>
__global__ __launch_bounds__(256, 8) void k_agg256(const unsigned short* __restrict__ t,
                                                   const int* __restrict__ row_ptr,
                                                   const int2* __restrict__ eg,
                                                   const float* __restrict__ bp,
                                                   unsigned short* __restrict__ outh,
                                                   const float* __restrict__ w3p,
                                                   float* __restrict__ t2, int n) {
    int lane = threadIdx.x & 63;
    int wave = threadIdx.x >> 6;
    int node = blockIdx.x * 4 + wave;
    if (node >= n) return;
    int half = lane >> 5;
    int fl = lane & 31;
    int beg = row_ptr[node], end = row_ptr[node + 1];
    f32x2 acc2[4];
#pragma unroll
    for (int i = 0; i < 4; ++i) { acc2[i].x = 0.f; acc2[i].y = 0.f; }
    const unsigned short* tp = t + fl * 8;

    int e = beg + half;
    for (; e + 10 < end; e += 12) {
        int2 a0 = ldnt2(eg + e), a1 = ldnt2(eg + e + 2), a2 = ldnt2(eg + e + 4);
        int2 a3 = ldnt2(eg + e + 6), a4 = ldnt2(eg + e + 8), a5 = ldnt2(eg + e + 10);
        uint4 v0 = *(const uint4*)(tp + (size_t)a0.x * 256);
        uint4 v1 = *(const uint4*)(tp + (size_t)a1.x * 256);
        uint4 v2 = *(const uint4*)(tp + (size_t)a2.x * 256);
        uint4 v3 = *(const uint4*)(tp + (size_t)a3.x * 256);
        uint4 v4 = *(const uint4*)(tp + (size_t)a4.x * 256);
        uint4 v5 = *(const uint4*)(tp + (size_t)a5.x * 256);
        acc8p(acc2, v0, __int_as_float(a0.y));
        acc8p(acc2, v1, __int_as_float(a1.y));
        acc8p(acc2, v2, __int_as_float(a2.y));
        acc8p(acc2, v3, __int_as_float(a3.y));
        acc8p(acc2, v4, __int_as_float(a4.y));
        acc8p(acc2, v5, __int_as_float(a5.y));
    }
    for (; e + 6 < end; e += 8) {
        int2 a0 = ldnt2(eg + e), a1 = ldnt2(eg + e + 2);
        int2 a2 = ldnt2(eg + e + 4), a3 = ldnt2(eg + e + 6);
        uint4 v0 = *(const uint4*)(tp + (size_t)a0.x * 256);
        uint4 v1 = *(const uint4*)(tp + (size_t)a1.x * 256);
        uint4 v2 = *(const uint4*)(tp + (size_t)a2.x * 256);
        uint4 v3 = *(const uint4*)(tp + (size_t)a3.x * 256);
        acc8p(acc2, v0, __int_as_float(a0.y));
        acc8p(acc2, v1, __int_as_float(a1.y));
        acc8p(acc2, v2, __int_as_float(a2.y));
        acc8p(acc2, v3, __int_as_float(a3.y));
    }
    for (; e + 2 < end; e += 4) {
        int2 a0 = ldnt2(eg + e), a1 = ldnt2(eg + e + 2);
        uint4 v0 = *(const uint4*)(tp + (size_t)a0.x * 256);
        uint4 v1 = *(const uint4*)(tp + (size_t)a1.x * 256);
        acc8p(acc2, v0, __int_as_float(a0.y));
        acc8p(acc2, v1, __int_as_float(a1.y));
    }
    if (e < end) {
        int2 a0 = ldnt2(eg + e);
        uint4 v0 = *(const uint4*)(tp + (size_t)a0.x * 256);
        acc8p(acc2, v0, __int_as_float(a0.y));
    }

    float va[8];
#pragma unroll
    for (int i = 0; i < 4; ++i) { va[2 * i] = acc2[i].x; va[2 * i + 1] = acc2[i].y; }
#pragma unroll
    for (int i = 0; i < 8; ++i) va[i] += __shfl_xor(va[i], 32);

    if (MODE == 0) {
        if (half == 0) {
            float4 bA = *(const float4*)(bp + fl * 8);
            float4 bB = *(const float4*)(bp + fl * 8 + 4);
            float r0 = fmaxf(va[0] + bA.x, 0.f), r1 = fmaxf(va[1] + bA.y, 0.f);
            float r2 = fmaxf(va[2] + bA.z, 0.f), r3 = fmaxf(va[3] + bA.w, 0.f);
            float r4 = fmaxf(va[4] + bB.x, 0.f), r5 = fmaxf(va[5] + bB.y, 0.f);
            float r6 = fmaxf(va[6] + bB.z, 0.f), r7 = fmaxf(va[7] + bB.w, 0.f);
            u32x4 w;
            w.x = (unsigned)f2bf(r0) | ((unsigned)f2bf(r1) << 16);
            w.y = (unsigned)f2bf(r2) | ((unsigned)f2bf(r3) << 16);
            w.z = (unsigned)f2bf(r4) | ((unsigned)f2bf(r5) << 16);
            w.w = (unsigned)f2bf(r6) | ((unsigned)f2bf(r7) << 16);
            __builtin_nontemporal_store(w, (u32x4*)(outh + (size_t)node * 256 + fl * 8));
        }
    } else {
        float4 bA = *(const float4*)(bp + fl * 8);
        float4 bB = *(const float4*)(bp + fl * 8 + 4);
        float r0 = fmaxf(va[0] + bA.x, 0.f), r1 = fmaxf(va[1] + bA.y, 0.f);
        float r2 = fmaxf(va[2] + bA.z, 0.f), r3 = fmaxf(va[3] + bA.w, 0.f);
        float r4 = fmaxf(va[4] + bB.x, 0.f), r5 = fmaxf(va[5] + bB.y, 0.f);
        float r6 = fmaxf(va[6] + bB.z, 0.f), r7 = fmaxf(va[7] + bB.w, 0.f);
        const float* wp = w3p + fl * 16;
        float4 wA = *(const float4*)(wp + 0);
        float4 wB = *(const float4*)(wp + 4);
        float4 wC = *(const float4*)(wp + 8);
        float4 wD = *(const float4*)(wp + 12);
        float s0 = r0 * wA.x + r1 * wA.z + r2 * wB.x + r3 * wB.z +
                   r4 * wC.x + r5 * wC.z + r6 * wD.x + r7 * wD.z;
        float s1 = r0 * wA.y + r1 * wA.w + r2 * wB.y + r3 * wB.w +
                   r4 * wC.y + r5 * wC.w + r6 * wD.y + r7 * wD.w;
#pragma unroll
        for (int off = 16; off > 0; off >>= 1) {
            s0 += __shfl_xor(s0, off);
            s1 += __shfl_xor(s1, off);
        }
        if (lane == 0) {
            f32x2 o;
            o.x = s0;
            o.y = s1;
            __builtin_nontemporal_store(o, (f32x2*)(t2 + (size_t)node * 2));
        }
    }
}

// ---------------- final aggregation of 2-wide rows: 4 lanes per node ----------------

__global__ void k_agg2(const float* __restrict__ t2,
                       const int* __restrict__ row_ptr,
                       const int2* __restrict__ eg,
                       const float* __restrict__ b3,
                       float* __restrict__ out, int n) {
    int tid = blockIdx.x * 256 + threadIdx.x;
    int node = tid >> 2;
    int sub = tid & 3;
    if (node >= n) return;
    int beg = row_ptr[node], end = row_ptr[node + 1];
    float a0 = 0.f, a1 = 0.f;
    for (int e = beg + sub; e < end; e += 4) {
        int2 m = ldnt2(eg + e);
        float w = __int_as_float(m.y);
        float2 v = *(const float2*)(t2 + (size_t)m.x * 2);
        a0 += w * v.x;
        a1 += w * v.y;
    }
    a0 += __shfl_xor(a0, 1); a1 += __shfl_xor(a1, 1);
    a0 += __shfl_xor(a0, 2); a1 += __shfl_xor(a1, 2);
    if (sub == 0) {
        out[(size_t)node * 2 + 0] = a0 + b3[0];
        out[(size_t)node * 2 + 1] = a1 + b3[1];
    }
}

// ---------------- launch ----------------

extern "C" void kernel_launch(void* const* d_in, const int* in_sizes, int n_in,
                              void* d_out, int out_size, void* d_ws, size_t ws_size,
                              hipStream_t stream) {
    const int N = N_NODES, E = N_EDGES;
    const float* x  = (const float*)d_in[0];
    const int* ei   = (const int*)d_in[1];
    const int* esrc = ei;
    const int* edst = ei + E;
    const float* W0 = (const float*)d_in[2];
    const float* b0 = (const float*)d_in[3];
    const float* W1 = (const float*)d_in[4];
    const float* b1 = (const float*)d_in[5];
    const float* W2 = (const float*)d_in[6];
    const float* b2 = (const float*)d_in[7];
    const float* W3 = (const float*)d_in[8];
    const float* b3 = (const float*)d_in[9];
    float* out = (float*)d_out;

    // workspace carve (8B-aligned regions first)
    unsigned short* Ahh = (unsigned short*)d_ws;            // N*256 bf16 h
    unsigned short* Tb  = Ahh + (size_t)N * 256;            // N*256 bf16 messages
    unsigned short* Wth = Tb + (size_t)N * 256;             // 3 x 256*256
    unsigned short* Wtl = Wth + 3 * 65536;                  // 3 x 256*256
    int2*  eg     = (int2*)(Wtl + 3 * 65536);               // E+N interleaved edge recs
    float* t2     = (float*)(eg + (E + N));                 // N*2
    float* bpw    = t2 + (size_t)N * 2;                     // 768 bias-perm + 512 W3-perm
    float* dis    = bpw + 1280;                             // N
    int*   cnt    = (int*)(dis + N);                        // N
    int*   row_ptr= cnt + N;                                // N+1
    int*   pos    = row_ptr + (N + 1);                      // N
    int*   blk    = pos + N;                                // cdiv(N,1024)

    const int NB = cdiv(N, 1024);

    // CSR build
    hipMemsetAsync(cnt, 0, (size_t)N * sizeof(int), stream);
    k_count<<<cdiv(E, 1024), 256, 0, stream>>>(edst, cnt, E);
    k_scan1<<<NB, 256, 0, stream>>>(cnt, row_ptr, dis, blk, N);
    k_scan2<<<1, 256, 0, stream>>>(blk, row_ptr + N, NB);
    k_scan3<<<NB, 256, 0, stream>>>(row_ptr, pos, blk, N);
    k_fill<<<cdiv(E + N, 256), 256, 0, stream>>>(esrc, edst, pos, dis, eg, E, N);

    const int agrid = cdiv(N, 4);  // in-order dispatch: preserves gather locality
    const long total4 = (long)N * 64;
    const int CA = cdiv((int)total4, 256);

    k_prep<<<49 + CA, 256, 0, stream>>>(W0, W1, W2, b0, b1, b2, W3, Wth, Wtl, bpw, x, Ahh, total4);

    // layer 0
    k_gemm_mfma<<<GEMM_GRID, 256, 0, stream>>>(Ahh, Wth, Wtl, Tb, N);
    k_agg256<0><<<agrid, 256, 0, stream>>>(Tb, row_ptr, eg, bpw, Ahh, nullptr, nullptr, N);
    // layer 1
    k_gemm_mfma<<<GEMM_GRID, 256, 0, stream>>>(Ahh, Wth + 65536, Wtl + 65536, Tb, N);
    k_agg256<0><<<agrid, 256, 0, stream>>>(Tb, row_ptr, eg, bpw + 256, Ahh, nullptr, nullptr, N);
    // layer 2 + fused [256,2] projection
    k_gemm_mfma<<<GEMM_GRID, 256, 0, stream>>>(Ahh, Wth + 2 * 65536, Wtl + 2 * 65536, Tb, N);
    k_agg256<1><<<agrid, 256, 0, stream>>>(Tb, row_ptr, eg, bpw + 512, nullptr, bpw + 768, t2, N);
    // layer 3 (no relu)
    k_agg2<<<cdiv(4 * N, 256), 256, 0, stream>>>(t2, row_ptr, eg, b3, out, N);
}

// Round 7
// 466.285 us; speedup vs baseline: 1.9104x; 1.9104x over previous
//
#include <hip/hip_runtime.h>

#define N_NODES 50000
#define N_EDGES 800000
// dims: IN=HID=256, OUT=2

static inline int cdiv(int a, int b) { return (a + b - 1) / b; }

typedef __attribute__((ext_vector_type(8))) short bf16x8;
typedef __attribute__((ext_vector_type(4))) float f32x4;
typedef __attribute__((ext_vector_type(2))) float f32x2;
typedef __attribute__((ext_vector_type(4))) unsigned int u32x4;

static __device__ __forceinline__ unsigned short f2bf(float f) {
    unsigned int u = __float_as_uint(f);
    unsigned int r = (u + 0x7FFF + ((u >> 16) & 1)) >> 16;  // RNE
    return (unsigned short)r;
}
static __device__ __forceinline__ float bf2f(unsigned short h) {
    return __uint_as_float((unsigned int)h << 16);
}
static __device__ __forceinline__ float bf_lo(unsigned int u) { return __uint_as_float(u << 16); }
static __device__ __forceinline__ float bf_hi(unsigned int u) { return __uint_as_float(u & 0xFFFF0000u); }

// nontemporal 8B load of an edge record (streamed once; keep L2 for the gather)
static __device__ __forceinline__ int2 ldnt2(const int2* p) {
    unsigned long long u = __builtin_nontemporal_load((const unsigned long long*)p);
    int2 r;
    r.x = (int)(u & 0xFFFFFFFFull);
    r.y = (int)(u >> 32);
    return r;
}

// accumulate 8 bf16 lanes of v (uint4) scaled by wgt into acc2[0..3] (float2 pairs)
static __device__ __forceinline__ void acc8p(f32x2* acc, uint4 v, float wgt) {
    f32x2 w2;
    w2.x = wgt;
    w2.y = wgt;
    f32x2 p;
    p.x = bf_lo(v.x); p.y = bf_hi(v.x); acc[0] += p * w2;
    p.x = bf_lo(v.y); p.y = bf_hi(v.y); acc[1] += p * w2;
    p.x = bf_lo(v.z); p.y = bf_hi(v.z); acc[2] += p * w2;
    p.x = bf_lo(v.w); p.y = bf_hi(v.w); acc[3] += p * w2;
}

// ---------------- CSR build ----------------

__global__ void k_count(const int* __restrict__ edst, int* cnt, int e) {
    int i = (blockIdx.x * 256 + threadIdx.x) * 4;
    if (i + 3 < e) {
        int4 v = *(const int4*)(edst + i);
        atomicAdd(&cnt[v.x], 1);
        atomicAdd(&cnt[v.y], 1);
        atomicAdd(&cnt[v.z], 1);
        atomicAdd(&cnt[v.w], 1);
    } else {
        for (int k = i; k < e; ++k) atomicAdd(&cnt[edst[k]], 1);
    }
}

__global__ __launch_bounds__(256) void k_scan1(const int* __restrict__ cnt,
                                               int* __restrict__ row_ptr,
                                               float* __restrict__ dis,
                                               int* __restrict__ blk, int n) {
    __shared__ int sums[256];
    int t = threadIdx.x;
    int base = blockIdx.x * 1024 + t * 4;
    int c0 = 0, c1 = 0, c2 = 0, c3 = 0;
    if (base + 3 < n) {
        int4 v = *(const int4*)(cnt + base);
        c0 = v.x + 1; c1 = v.y + 1; c2 = v.z + 1; c3 = v.w + 1;  // +1 self-loop
    } else {
        if (base + 0 < n) c0 = cnt[base + 0] + 1;
        if (base + 1 < n) c1 = cnt[base + 1] + 1;
        if (base + 2 < n) c2 = cnt[base + 2] + 1;
        if (base + 3 < n) c3 = cnt[base + 3] + 1;
    }
    int s = c0 + c1 + c2 + c3;
    sums[t] = s;
    __syncthreads();
    int x = s;
    for (int off = 1; off < 256; off <<= 1) {
        int y = (t >= off) ? sums[t - off] : 0;
        __syncthreads();
        x += y;
        sums[t] = x;
        __syncthreads();
    }
    int excl = x - s;
    if (base + 0 < n) { row_ptr[base + 0] = excl;                dis[base + 0] = rsqrtf((float)c0); }
    if (base + 1 < n) { row_ptr[base + 1] = excl + c0;           dis[base + 1] = rsqrtf((float)c1); }
    if (base + 2 < n) { row_ptr[base + 2] = excl + c0 + c1;      dis[base + 2] = rsqrtf((float)c2); }
    if (base + 3 < n) { row_ptr[base + 3] = excl + c0 + c1 + c2; dis[base + 3] = rsqrtf((float)c3); }
    if (t == 255) blk[blockIdx.x] = x;
}

__global__ __launch_bounds__(256) void k_scan2(int* __restrict__ blk,
                                               int* __restrict__ row_ptr_n, int nb) {
    __shared__ int sums[256];
    int t = threadIdx.x;
    int s = (t < nb) ? blk[t] : 0;
    sums[t] = s;
    __syncthreads();
    int x = s;
    for (int off = 1; off < 256; off <<= 1) {
        int y = (t >= off) ? sums[t - off] : 0;
        __syncthreads();
        x += y;
        sums[t] = x;
        __syncthreads();
    }
    if (t < nb) blk[t] = x - s;
    if (t == 255) row_ptr_n[0] = x;
}

__global__ __launch_bounds__(256) void k_scan3(int* __restrict__ row_ptr,
                                               int* __restrict__ pos,
                                               const int* __restrict__ blk, int n) {
    int base = blockIdx.x * 1024 + threadIdx.x * 4;
    int off = blk[blockIdx.x];
#pragma unroll
    for (int i = 0; i < 4; ++i) {
        int idx = base + i;
        if (idx < n) {
            int v = row_ptr[idx] + off;
            row_ptr[idx] = v;
            pos[idx] = v;
        }
    }
}

// merged: items [0,E) = edges, [E, E+N) = self-loops.
__global__ void k_fill(const int* __restrict__ esrc, const int* __restrict__ edst,
                       int* pos, const float* __restrict__ dis,
                       int2* __restrict__ eg, int e, int n) {
    int i = blockIdx.x * 256 + threadIdx.x;
    if (i < e) {
        int s = esrc[i], d = edst[i];
        int p = atomicAdd(&pos[d], 1);
        unsigned long long u = (unsigned long long)(unsigned int)s |
                               ((unsigned long long)(unsigned int)__float_as_int(dis[s] * dis[d]) << 32);
        __builtin_nontemporal_store(u, (unsigned long long*)&eg[p]);
    } else if (i < e + n) {
        int v = i - e;
        int p = atomicAdd(&pos[v], 1);
        float dv = dis[v];
        unsigned long long u = (unsigned long long)(unsigned int)v |
                               ((unsigned long long)(unsigned int)__float_as_int(dv * dv) << 32);
        __builtin_nontemporal_store(u, (unsigned long long*)&eg[p]);
    }
}

// ---------------- prep ----------------
// blocks 0..47: weight split via LDS 64x64 tile transpose (coalesced both sides).
// block 48: bias/W3 permute. blocks 49+: x -> bf16 cast.

__global__ __launch_bounds__(256) void k_prep(const float* __restrict__ W0,
                                              const float* __restrict__ W1,
                                              const float* __restrict__ W2,
                                              const float* __restrict__ b0,
                                              const float* __restrict__ b1,
                                              const float* __restrict__ b2,
                                              const float* __restrict__ W3,
                                              unsigned short* __restrict__ Wth,
                                              unsigned short* __restrict__ Wtl,
                                              float* __restrict__ bpw,
                                              const float* __restrict__ X,
                                              unsigned short* __restrict__ Xh, long total4) {
    if (blockIdx.x < 48) {
        __shared__ float tile[64][65];
        int layer = blockIdx.x / 16;
        int tid = blockIdx.x % 16;
        int ti = tid >> 2, tj = tid & 3;  // ti: k-tile, tj: n-tile
        const float* W = layer == 0 ? W0 : (layer == 1 ? W1 : W2);
        int r0 = ti * 64, n0 = tj * 64;
        int rr = threadIdx.x >> 4;          // 0..15
        int cc = (threadIdx.x & 15) * 4;    // 0..60
#pragma unroll
        for (int j = 0; j < 4; ++j) {
            float4 v = *(const float4*)(W + (size_t)(r0 + rr + j * 16) * 256 + n0 + cc);
            tile[rr + j * 16][cc + 0] = v.x;
            tile[rr + j * 16][cc + 1] = v.y;
            tile[rr + j * 16][cc + 2] = v.z;
            tile[rr + j * 16][cc + 3] = v.w;
        }
        __syncthreads();
        int pl = threadIdx.x & 63;   // p within tile
        int ng = threadIdx.x >> 6;   // 0..3
        int kl = (layer != 0) ? ((pl & 3) * 16 + (pl >> 2)) : pl;  // logc within 64
#pragma unroll
        for (int i = 0; i < 16; ++i) {
            int nl = ng * 16 + i;
            float v = tile[kl][nl];
            unsigned short h = f2bf(v);
            size_t o = (size_t)layer * 65536 + (size_t)(n0 + nl) * 256 + r0 + pl;
            Wth[o] = h;
            Wtl[o] = f2bf(v - bf2f(h));
        }
    } else if (blockIdx.x == 48) {
        int p = threadIdx.x;
        int pl = p & 63;
        int c = (p & ~63) + (pl & 3) * 16 + (pl >> 2);  // logc
        bpw[p] = b0[c];
        bpw[256 + p] = b1[c];
        bpw[512 + p] = b2[c];
        bpw[768 + p * 2 + 0] = W3[(size_t)c * 2 + 0];
        bpw[768 + p * 2 + 1] = W3[(size_t)c * 2 + 1];
    } else {
        long i = (long)(blockIdx.x - 49) * 256 + threadIdx.x;
        if (i >= total4) return;
        float4 v = *(const float4*)(X + i * 4);
        ushort4 h;
        h.x = f2bf(v.x);
        h.y = f2bf(v.y);
        h.z = f2bf(v.z);
        h.w = f2bf(v.w);
        *(ushort4*)(Xh + i * 4) = h;
    }
}

// ---------------- MFMA GEMM: Ah(bf16)[M,256] @ Wsplit -> bf16 [M,256] ----
// EXACT R1 form (best measured: 465.8 us total). block: 256 rows x 64 cols;
// wave: 64 rows (4 mt) x 64 cols (4 nt). C = ah*bh + ah*bl per kc.
// LDS: Wh full-K (33.8 KB) + Wl half-K (17.4 KB) restaged once mid-kernel
// -> 51.2 KB -> 3 blocks/CU. No launch-bounds min-wave pressure (R6 lesson:
// forcing 6 waves/EU spilled the 64-VGPR accumulator to scratch, 15x writes).

#define GEMM_RB 196  // cdiv(50000,256)

__global__ __launch_bounds__(256) void k_gemm_mfma(const unsigned short* __restrict__ Ah,
                                                   const unsigned short* __restrict__ Wth,
                                                   const unsigned short* __restrict__ Wtl,
                                                   unsigned short* __restrict__ C, int M) {
    __shared__ unsigned short Wh[64][264];  // full K, pad 8 -> 2-way (free)
    __shared__ unsigned short Wl[64][136];  // half K, pad 8
    int rowblk = blockIdx.x % GEMM_RB;
    int colblk = blockIdx.x / GEMM_RB;
    int c0 = colblk * 64;
    int m0 = rowblk * 256;
    int t = threadIdx.x;
    int sr = t >> 2;

    {   // stage Wh (full 256 k) + Wl first half (k 0..127)
        int hk0 = (t & 3) * 64;
        const unsigned short* gh = Wth + (size_t)(c0 + sr) * 256 + hk0;
        unsigned short* lh = &Wh[sr][hk0];
#pragma unroll
        for (int i = 0; i < 8; ++i)
            *(uint4*)(lh + i * 8) = *(const uint4*)(gh + i * 8);
        int lk0 = (t & 3) * 32;
        const unsigned short* gl = Wtl + (size_t)(c0 + sr) * 256 + lk0;
        unsigned short* ll = &Wl[sr][lk0];
#pragma unroll
        for (int i = 0; i < 4; ++i)
            *(uint4*)(ll + i * 8) = *(const uint4*)(gl + i * 8);
    }
    __syncthreads();

    int lane = t & 63, wave = t >> 6;
    int quad = lane >> 4, l16 = lane & 15;

    const unsigned short* aph[4];
#pragma unroll
    for (int mt = 0; mt < 4; ++mt) {
        int m = m0 + wave * 64 + mt * 16 + l16;
        if (m >= M) m = M - 1;  // clamp loads; stores guarded
        aph[mt] = Ah + (size_t)m * 256 + quad * 8;
    }

    f32x4 acc[4][4];
#pragma unroll
    for (int i = 0; i < 4; ++i)
#pragma unroll
        for (int j = 0; j < 4; ++j) acc[i][j] = (f32x4){0.f, 0.f, 0.f, 0.f};

#pragma unroll 2
    for (int kc = 0; kc < 4; ++kc) {
        int ko = kc * 32;
        bf16x8 ahf[4];
#pragma unroll
        for (int mt = 0; mt < 4; ++mt) ahf[mt] = *(const bf16x8*)(aph[mt] + ko);
#pragma unroll
        for (int nt = 0; nt < 4; ++nt) {
            bf16x8 bh = *(const bf16x8*)&Wh[nt * 16 + l16][ko + quad * 8];
            bf16x8 bl = *(const bf16x8*)&Wl[nt * 16 + l16][ko + quad * 8];
#pragma unroll
            for (int mt = 0; mt < 4; ++mt) {
                acc[mt][nt] = __builtin_amdgcn_mfma_f32_16x16x32_bf16(ahf[mt], bh, acc[mt][nt], 0, 0, 0);
                acc[mt][nt] = __builtin_amdgcn_mfma_f32_16x16x32_bf16(ahf[mt], bl, acc[mt][nt], 0, 0, 0);
            }
        }
    }

    __syncthreads();  // all reads of Wl half 1 done
    {   // restage Wl second half (k 128..255)
        int lk0 = (t & 3) * 32;
        const unsigned short* gl = Wtl + (size_t)(c0 + sr) * 256 + 128 + lk0;
        unsigned short* ll = &Wl[sr][lk0];
#pragma unroll
        for (int i = 0; i < 4; ++i)
            *(uint4*)(ll + i * 8) = *(const uint4*)(gl + i * 8);
    }
    __syncthreads();

#pragma unroll 2
    for (int kc = 4; kc < 8; ++kc) {
        int ko = kc * 32;
        int kol = ko - 128;
        bf16x8 ahf[4];
#pragma unroll
        for (int mt = 0; mt < 4; ++mt) ahf[mt] = *(const bf16x8*)(aph[mt] + ko);
#pragma unroll
        for (int nt = 0; nt < 4; ++nt) {
            bf16x8 bh = *(const bf16x8*)&Wh[nt * 16 + l16][ko + quad * 8];
            bf16x8 bl = *(const bf16x8*)&Wl[nt * 16 + l16][kol + quad * 8];
#pragma unroll
            for (int mt = 0; mt < 4; ++mt) {
                acc[mt][nt] = __builtin_amdgcn_mfma_f32_16x16x32_bf16(ahf[mt], bh, acc[mt][nt], 0, 0, 0);
                acc[mt][nt] = __builtin_amdgcn_mfma_f32_16x16x32_bf16(ahf[mt], bl, acc[mt][nt], 0, 0, 0);
            }
        }
    }

    // permuted store: per (mt,r) one ushort4 at phys cols c0 + l16*4 + {0..3}
#pragma unroll
    for (int mt = 0; mt < 4; ++mt) {
#pragma unroll
        for (int r = 0; r < 4; ++r) {
            int row = m0 + wave * 64 + mt * 16 + quad * 4 + r;
            if (row < M) {
                ushort4 sv;
                sv.x = f2bf(acc[mt][0][r]);
                sv.y = f2bf(acc[mt][1][r]);
                sv.z = f2bf(acc[mt][2][r]);
                sv.w = f2bf(acc[mt][3][r]);
                *(ushort4*)(C + (size_t)row * 256 + c0 + l16 * 4) = sv;
            }
        }
    }
}

// ---------------- aggregation dim=256 over (permuted) bf16 messages ----------------
// one block per 4 nodes, in-dispatch-order (preserves gather L2 locality —
// measured R1 vs R2). wave per node, half-wave per edge, 6 edges in flight.
// MODE 0: bias+relu -> bf16 store. MODE 1: fused [256,2] projection -> t2.

template <int MODE>
__global__ __launch_bounds__(256, 8) void k_agg256(const unsigned short* __restrict__ t,
                                                   const int* __restrict__ row_ptr,
                                                   const int2* __restrict__ eg,
                                                   const float* __restrict__ bp,
                                                   unsigned short* __restrict__ outh,
                                                   const float* __restrict__ w3p,
                                                   float* __restrict__ t2, int n) {
    int lane = threadIdx.x & 63;
    int wave = threadIdx.x >> 6;
    int node = blockIdx.x * 4 + wave;
    if (node >= n) return;
    int half = lane >> 5;
    int fl = lane & 31;
    int beg = row_ptr[node], end = row_ptr[node + 1];
    f32x2 acc2[4];
#pragma unroll
    for (int i = 0; i < 4; ++i) { acc2[i].x = 0.f; acc2[i].y = 0.f; }
    const unsigned short* tp = t + fl * 8;

    int e = beg + half;
    for (; e + 10 < end; e += 12) {
        int2 a0 = ldnt2(eg + e), a1 = ldnt2(eg + e + 2), a2 = ldnt2(eg + e + 4);
        int2 a3 = ldnt2(eg + e + 6), a4 = ldnt2(eg + e + 8), a5 = ldnt2(eg + e + 10);
        uint4 v0 = *(const uint4*)(tp + (size_t)a0.x * 256);
        uint4 v1 = *(const uint4*)(tp + (size_t)a1.x * 256);
        uint4 v2 = *(const uint4*)(tp + (size_t)a2.x * 256);
        uint4 v3 = *(const uint4*)(tp + (size_t)a3.x * 256);
        uint4 v4 = *(const uint4*)(tp + (size_t)a4.x * 256);
        uint4 v5 = *(const uint4*)(tp + (size_t)a5.x * 256);
        acc8p(acc2, v0, __int_as_float(a0.y));
        acc8p(acc2, v1, __int_as_float(a1.y));
        acc8p(acc2, v2, __int_as_float(a2.y));
        acc8p(acc2, v3, __int_as_float(a3.y));
        acc8p(acc2, v4, __int_as_float(a4.y));
        acc8p(acc2, v5, __int_as_float(a5.y));
    }
    for (; e + 6 < end; e += 8) {
        int2 a0 = ldnt2(eg + e), a1 = ldnt2(eg + e + 2);
        int2 a2 = ldnt2(eg + e + 4), a3 = ldnt2(eg + e + 6);
        uint4 v0 = *(const uint4*)(tp + (size_t)a0.x * 256);
        uint4 v1 = *(const uint4*)(tp + (size_t)a1.x * 256);
        uint4 v2 = *(const uint4*)(tp + (size_t)a2.x * 256);
        uint4 v3 = *(const uint4*)(tp + (size_t)a3.x * 256);
        acc8p(acc2, v0, __int_as_float(a0.y));
        acc8p(acc2, v1, __int_as_float(a1.y));
        acc8p(acc2, v2, __int_as_float(a2.y));
        acc8p(acc2, v3, __int_as_float(a3.y));
    }
    for (; e + 2 < end; e += 4) {
        int2 a0 = ldnt2(eg + e), a1 = ldnt2(eg + e + 2);
        uint4 v0 = *(const uint4*)(tp + (size_t)a0.x * 256);
        uint4 v1 = *(const uint4*)(tp + (size_t)a1.x * 256);
        acc8p(acc2, v0, __int_as_float(a0.y));
        acc8p(acc2, v1, __int_as_float(a1.y));
    }
    if (e < end) {
        int2 a0 = ldnt2(eg + e);
        uint4 v0 = *(const uint4*)(tp + (size_t)a0.x * 256);
        acc8p(acc2, v0, __int_as_float(a0.y));
    }

    float va[8];
#pragma unroll
    for (int i = 0; i < 4; ++i) { va[2 * i] = acc2[i].x; va[2 * i + 1] = acc2[i].y; }
#pragma unroll
    for (int i = 0; i < 8; ++i) va[i] += __shfl_xor(va[i], 32);

    if (MODE == 0) {
        if (half == 0) {
            float4 bA = *(const float4*)(bp + fl * 8);
            float4 bB = *(const float4*)(bp + fl * 8 + 4);
            float r0 = fmaxf(va[0] + bA.x, 0.f), r1 = fmaxf(va[1] + bA.y, 0.f);
            float r2 = fmaxf(va[2] + bA.z, 0.f), r3 = fmaxf(va[3] + bA.w, 0.f);
            float r4 = fmaxf(va[4] + bB.x, 0.f), r5 = fmaxf(va[5] + bB.y, 0.f);
            float r6 = fmaxf(va[6] + bB.z, 0.f), r7 = fmaxf(va[7] + bB.w, 0.f);
            u32x4 w;
            w.x = (unsigned)f2bf(r0) | ((unsigned)f2bf(r1) << 16);
            w.y = (unsigned)f2bf(r2) | ((unsigned)f2bf(r3) << 16);
            w.z = (unsigned)f2bf(r4) | ((unsigned)f2bf(r5) << 16);
            w.w = (unsigned)f2bf(r6) | ((unsigned)f2bf(r7) << 16);
            __builtin_nontemporal_store(w, (u32x4*)(outh + (size_t)node * 256 + fl * 8));
        }
    } else {
        float4 bA = *(const float4*)(bp + fl * 8);
        float4 bB = *(const float4*)(bp + fl * 8 + 4);
        float r0 = fmaxf(va[0] + bA.x, 0.f), r1 = fmaxf(va[1] + bA.y, 0.f);
        float r2 = fmaxf(va[2] + bA.z, 0.f), r3 = fmaxf(va[3] + bA.w, 0.f);
        float r4 = fmaxf(va[4] + bB.x, 0.f), r5 = fmaxf(va[5] + bB.y, 0.f);
        float r6 = fmaxf(va[6] + bB.z, 0.f), r7 = fmaxf(va[7] + bB.w, 0.f);
        const float* wp = w3p + fl * 16;
        float4 wA = *(const float4*)(wp + 0);
        float4 wB = *(const float4*)(wp + 4);
        float4 wC = *(const float4*)(wp + 8);
        float4 wD = *(const float4*)(wp + 12);
        float s0 = r0 * wA.x + r1 * wA.z + r2 * wB.x + r3 * wB.z +
                   r4 * wC.x + r5 * wC.z + r6 * wD.x + r7 * wD.z;
        float s1 = r0 * wA.y + r1 * wA.w + r2 * wB.y + r3 * wB.w +
                   r4 * wC.y + r5 * wC.w + r6 * wD.y + r7 * wD.w;
#pragma unroll
        for (int off = 16; off > 0; off >>= 1) {
            s0 += __shfl_xor(s0, off);
            s1 += __shfl_xor(s1, off);
        }
        if (lane == 0) {
            f32x2 o;
            o.x = s0;
            o.y = s1;
            __builtin_nontemporal_store(o, (f32x2*)(t2 + (size_t)node * 2));
        }
    }
}

// ---------------- final aggregation of 2-wide rows: 4 lanes per node ----------------

__global__ void k_agg2(const float* __restrict__ t2,
                       const int* __restrict__ row_ptr,
                       const int2* __restrict__ eg,
                       const float* __restrict__ b3,
                       float* __restrict__ out, int n) {
    int tid = blockIdx.x * 256 + threadIdx.x;
    int node = tid >> 2;
    int sub = tid & 3;
    if (node >= n) return;
    int beg = row_ptr[node], end = row_ptr[node + 1];
    float a0 = 0.f, a1 = 0.f;
    for (int e = beg + sub; e < end; e += 4) {
        int2 m = ldnt2(eg + e);
        float w = __int_as_float(m.y);
        float2 v = *(const float2*)(t2 + (size_t)m.x * 2);
        a0 += w * v.x;
        a1 += w * v.y;
    }
    a0 += __shfl_xor(a0, 1); a1 += __shfl_xor(a1, 1);
    a0 += __shfl_xor(a0, 2); a1 += __shfl_xor(a1, 2);
    if (sub == 0) {
        out[(size_t)node * 2 + 0] = a0 + b3[0];
        out[(size_t)node * 2 + 1] = a1 + b3[1];
    }
}

// ---------------- launch ----------------

extern "C" void kernel_launch(void* const* d_in, const int* in_sizes, int n_in,
                              void* d_out, int out_size, void* d_ws, size_t ws_size,
                              hipStream_t stream) {
    const int N = N_NODES, E = N_EDGES;
    const float* x  = (const float*)d_in[0];
    const int* ei   = (const int*)d_in[1];
    const int* esrc = ei;
    const int* edst = ei + E;
    const float* W0 = (const float*)d_in[2];
    const float* b0 = (const float*)d_in[3];
    const float* W1 = (const float*)d_in[4];
    const float* b1 = (const float*)d_in[5];
    const float* W2 = (const float*)d_in[6];
    const float* b2 = (const float*)d_in[7];
    const float* W3 = (const float*)d_in[8];
    const float* b3 = (const float*)d_in[9];
    float* out = (float*)d_out;

    // workspace carve (8B-aligned regions first)
    unsigned short* Ahh = (unsigned short*)d_ws;            // N*256 bf16 h
    unsigned short* Tb  = Ahh + (size_t)N * 256;            // N*256 bf16 messages
    unsigned short* Wth = Tb + (size_t)N * 256;             // 3 x 256*256
    unsigned short* Wtl = Wth + 3 * 65536;                  // 3 x 256*256
    int2*  eg     = (int2*)(Wtl + 3 * 65536);               // E+N interleaved edge recs
    float* t2     = (float*)(eg + (E + N));                 // N*2
    float* bpw    = t2 + (size_t)N * 2;                     // 768 bias-perm + 512 W3-perm
    float* dis    = bpw + 1280;                             // N
    int*   cnt    = (int*)(dis + N);                        // N
    int*   row_ptr= cnt + N;                                // N+1
    int*   pos    = row_ptr + (N + 1);                      // N
    int*   blk    = pos + N;                                // cdiv(N,1024)

    const int NB = cdiv(N, 1024);

    // CSR build
    hipMemsetAsync(cnt, 0, (size_t)N * sizeof(int), stream);
    k_count<<<cdiv(E, 1024), 256, 0, stream>>>(edst, cnt, E);
    k_scan1<<<NB, 256, 0, stream>>>(cnt, row_ptr, dis, blk, N);
    k_scan2<<<1, 256, 0, stream>>>(blk, row_ptr + N, NB);
    k_scan3<<<NB, 256, 0, stream>>>(row_ptr, pos, blk, N);
    k_fill<<<cdiv(E + N, 256), 256, 0, stream>>>(esrc, edst, pos, dis, eg, E, N);

    const int ggrid = GEMM_RB * 4;
    const int agrid = cdiv(N, 4);  // in-order dispatch: preserves gather locality
    const long total4 = (long)N * 64;
    const int CA = cdiv((int)total4, 256);

    k_prep<<<49 + CA, 256, 0, stream>>>(W0, W1, W2, b0, b1, b2, W3, Wth, Wtl, bpw, x, Ahh, total4);

    // layer 0
    k_gemm_mfma<<<ggrid, 256, 0, stream>>>(Ahh, Wth, Wtl, Tb, N);
    k_agg256<0><<<agrid, 256, 0, stream>>>(Tb, row_ptr, eg, bpw, Ahh, nullptr, nullptr, N);
    // layer 1
    k_gemm_mfma<<<ggrid, 256, 0, stream>>>(Ahh, Wth + 65536, Wtl + 65536, Tb, N);
    k_agg256<0><<<agrid, 256, 0, stream>>>(Tb, row_ptr, eg, bpw + 256, Ahh, nullptr, nullptr, N);
    // layer 2 + fused [256,2] projection
    k_gemm_mfma<<<ggrid, 256, 0, stream>>>(Ahh, Wth + 2 * 65536, Wtl + 2 * 65536, Tb, N);
    k_agg256<1><<<agrid, 256, 0, stream>>>(Tb, row_ptr, eg, bpw + 512, nullptr, bpw + 768, t2, N);
    // layer 3 (no relu)
    k_agg2<<<cdiv(4 * N, 256), 256, 0, stream>>>(t2, row_ptr, eg, b3, out, N);
}

// Round 8
// 460.529 us; speedup vs baseline: 1.9342x; 1.0125x over previous
//
#include <hip/hip_runtime.h>

#define N_NODES 50000
#define N_EDGES 800000
// dims: IN=HID=256, OUT=2

static inline int cdiv(int a, int b) { return (a + b - 1) / b; }

typedef __attribute__((ext_vector_type(8))) short bf16x8;
typedef __attribute__((ext_vector_type(4))) float f32x4;
typedef __attribute__((ext_vector_type(2))) float f32x2;
typedef __attribute__((ext_vector_type(4))) unsigned int u32x4;

static __device__ __forceinline__ unsigned short f2bf(float f) {
    unsigned int u = __float_as_uint(f);
    unsigned int r = (u + 0x7FFF + ((u >> 16) & 1)) >> 16;  // RNE
    return (unsigned short)r;
}
static __device__ __forceinline__ float bf2f(unsigned short h) {
    return __uint_as_float((unsigned int)h << 16);
}
static __device__ __forceinline__ float bf_lo(unsigned int u) { return __uint_as_float(u << 16); }
static __device__ __forceinline__ float bf_hi(unsigned int u) { return __uint_as_float(u & 0xFFFF0000u); }

// nontemporal 8B load of an edge record (streamed once; keep L2 for the gather)
static __device__ __forceinline__ int2 ldnt2(const int2* p) {
    unsigned long long u = __builtin_nontemporal_load((const unsigned long long*)p);
    int2 r;
    r.x = (int)(u & 0xFFFFFFFFull);
    r.y = (int)(u >> 32);
    return r;
}

// accumulate 8 bf16 lanes of v (uint4) scaled by wgt into acc2[0..3] (float2 pairs)
static __device__ __forceinline__ void acc8p(f32x2* acc, uint4 v, float wgt) {
    f32x2 w2;
    w2.x = wgt;
    w2.y = wgt;
    f32x2 p;
    p.x = bf_lo(v.x); p.y = bf_hi(v.x); acc[0] += p * w2;
    p.x = bf_lo(v.y); p.y = bf_hi(v.y); acc[1] += p * w2;
    p.x = bf_lo(v.z); p.y = bf_hi(v.z); acc[2] += p * w2;
    p.x = bf_lo(v.w); p.y = bf_hi(v.w); acc[3] += p * w2;
}

// ---------------- init: edge count + weight split + bias/W3 permute + x cast ----
// One launch for all independent front-end work (count is atomic-bound, the rest
// is BW-bound — they co-schedule). Block ranges:
//   [0, CB)            : edge-degree count (4 edges/thread)
//   [CB, CB+48)        : weight split via LDS 64x64 tile transpose
//   CB+48              : bias/W3 permute
//   [CB+49, CB+49+CA)  : x -> bf16 cast

#define CNT_B (((N_EDGES) + 1023) / 1024)  // 782

__global__ __launch_bounds__(256) void k_init(const int* __restrict__ edst, int* cnt, int e,
                                              const float* __restrict__ W0,
                                              const float* __restrict__ W1,
                                              const float* __restrict__ W2,
                                              const float* __restrict__ b0,
                                              const float* __restrict__ b1,
                                              const float* __restrict__ b2,
                                              const float* __restrict__ W3,
                                              unsigned short* __restrict__ Wth,
                                              unsigned short* __restrict__ Wtl,
                                              float* __restrict__ bpw,
                                              const float* __restrict__ X,
                                              unsigned short* __restrict__ Xh, long total4) {
    if (blockIdx.x < CNT_B) {
        int i = (blockIdx.x * 256 + threadIdx.x) * 4;
        if (i + 3 < e) {
            int4 v = *(const int4*)(edst + i);
            atomicAdd(&cnt[v.x], 1);
            atomicAdd(&cnt[v.y], 1);
            atomicAdd(&cnt[v.z], 1);
            atomicAdd(&cnt[v.w], 1);
        } else {
            for (int k = i; k < e; ++k) atomicAdd(&cnt[edst[k]], 1);
        }
    } else if (blockIdx.x < CNT_B + 48) {
        __shared__ float tile[64][65];
        int wb = blockIdx.x - CNT_B;
        int layer = wb / 16;
        int tid = wb % 16;
        int ti = tid >> 2, tj = tid & 3;  // ti: k-tile, tj: n-tile
        const float* W = layer == 0 ? W0 : (layer == 1 ? W1 : W2);
        int r0 = ti * 64, n0 = tj * 64;
        int rr = threadIdx.x >> 4;          // 0..15
        int cc = (threadIdx.x & 15) * 4;    // 0..60
#pragma unroll
        for (int j = 0; j < 4; ++j) {
            float4 v = *(const float4*)(W + (size_t)(r0 + rr + j * 16) * 256 + n0 + cc);
            tile[rr + j * 16][cc + 0] = v.x;
            tile[rr + j * 16][cc + 1] = v.y;
            tile[rr + j * 16][cc + 2] = v.z;
            tile[rr + j * 16][cc + 3] = v.w;
        }
        __syncthreads();
        int pl = threadIdx.x & 63;   // p within tile
        int ng = threadIdx.x >> 6;   // 0..3
        int kl = (layer != 0) ? ((pl & 3) * 16 + (pl >> 2)) : pl;  // logc within 64
#pragma unroll
        for (int i = 0; i < 16; ++i) {
            int nl = ng * 16 + i;
            float v = tile[kl][nl];
            unsigned short h = f2bf(v);
            size_t o = (size_t)layer * 65536 + (size_t)(n0 + nl) * 256 + r0 + pl;
            Wth[o] = h;
            Wtl[o] = f2bf(v - bf2f(h));
        }
    } else if (blockIdx.x == CNT_B + 48) {
        int p = threadIdx.x;
        int pl = p & 63;
        int c = (p & ~63) + (pl & 3) * 16 + (pl >> 2);  // logc
        bpw[p] = b0[c];
        bpw[256 + p] = b1[c];
        bpw[512 + p] = b2[c];
        bpw[768 + p * 2 + 0] = W3[(size_t)c * 2 + 0];
        bpw[768 + p * 2 + 1] = W3[(size_t)c * 2 + 1];
    } else {
        long i = (long)(blockIdx.x - (CNT_B + 49)) * 256 + threadIdx.x;
        if (i >= total4) return;
        float4 v = *(const float4*)(X + i * 4);
        ushort4 h;
        h.x = f2bf(v.x);
        h.y = f2bf(v.y);
        h.z = f2bf(v.z);
        h.w = f2bf(v.w);
        *(ushort4*)(Xh + i * 4) = h;
    }
}

// ---------------- CSR scans + fill ----------------

__global__ __launch_bounds__(256) void k_scan1(const int* __restrict__ cnt,
                                               int* __restrict__ row_ptr,
                                               float* __restrict__ dis,
                                               int* __restrict__ blk, int n) {
    __shared__ int sums[256];
    int t = threadIdx.x;
    int base = blockIdx.x * 1024 + t * 4;
    int c0 = 0, c1 = 0, c2 = 0, c3 = 0;
    if (base + 3 < n) {
        int4 v = *(const int4*)(cnt + base);
        c0 = v.x + 1; c1 = v.y + 1; c2 = v.z + 1; c3 = v.w + 1;  // +1 self-loop
    } else {
        if (base + 0 < n) c0 = cnt[base + 0] + 1;
        if (base + 1 < n) c1 = cnt[base + 1] + 1;
        if (base + 2 < n) c2 = cnt[base + 2] + 1;
        if (base + 3 < n) c3 = cnt[base + 3] + 1;
    }
    int s = c0 + c1 + c2 + c3;
    sums[t] = s;
    __syncthreads();
    int x = s;
    for (int off = 1; off < 256; off <<= 1) {
        int y = (t >= off) ? sums[t - off] : 0;
        __syncthreads();
        x += y;
        sums[t] = x;
        __syncthreads();
    }
    int excl = x - s;
    if (base + 0 < n) { row_ptr[base + 0] = excl;                dis[base + 0] = rsqrtf((float)c0); }
    if (base + 1 < n) { row_ptr[base + 1] = excl + c0;           dis[base + 1] = rsqrtf((float)c1); }
    if (base + 2 < n) { row_ptr[base + 2] = excl + c0 + c1;      dis[base + 2] = rsqrtf((float)c2); }
    if (base + 3 < n) { row_ptr[base + 3] = excl + c0 + c1 + c2; dis[base + 3] = rsqrtf((float)c3); }
    if (t == 255) blk[blockIdx.x] = x;
}

__global__ __launch_bounds__(256) void k_scan2(int* __restrict__ blk,
                                               int* __restrict__ row_ptr_n, int nb) {
    __shared__ int sums[256];
    int t = threadIdx.x;
    int s = (t < nb) ? blk[t] : 0;
    sums[t] = s;
    __syncthreads();
    int x = s;
    for (int off = 1; off < 256; off <<= 1) {
        int y = (t >= off) ? sums[t - off] : 0;
        __syncthreads();
        x += y;
        sums[t] = x;
        __syncthreads();
    }
    if (t < nb) blk[t] = x - s;
    if (t == 255) row_ptr_n[0] = x;
}

__global__ __launch_bounds__(256) void k_scan3(int* __restrict__ row_ptr,
                                               int* __restrict__ pos,
                                               const int* __restrict__ blk, int n) {
    int base = blockIdx.x * 1024 + threadIdx.x * 4;
    int off = blk[blockIdx.x];
#pragma unroll
    for (int i = 0; i < 4; ++i) {
        int idx = base + i;
        if (idx < n) {
            int v = row_ptr[idx] + off;
            row_ptr[idx] = v;
            pos[idx] = v;
        }
    }
}

// merged: items [0,E) = edges, [E, E+N) = self-loops.
__global__ void k_fill(const int* __restrict__ esrc, const int* __restrict__ edst,
                       int* pos, const float* __restrict__ dis,
                       int2* __restrict__ eg, int e, int n) {
    int i = blockIdx.x * 256 + threadIdx.x;
    if (i < e) {
        int s = esrc[i], d = edst[i];
        int p = atomicAdd(&pos[d], 1);
        unsigned long long u = (unsigned long long)(unsigned int)s |
                               ((unsigned long long)(unsigned int)__float_as_int(dis[s] * dis[d]) << 32);
        __builtin_nontemporal_store(u, (unsigned long long*)&eg[p]);
    } else if (i < e + n) {
        int v = i - e;
        int p = atomicAdd(&pos[v], 1);
        float dv = dis[v];
        unsigned long long u = (unsigned long long)(unsigned int)v |
                               ((unsigned long long)(unsigned int)__float_as_int(dv * dv) << 32);
        __builtin_nontemporal_store(u, (unsigned long long*)&eg[p]);
    }
}

// ---------------- MFMA GEMM: Ah(bf16)[M,256] @ Wsplit -> bf16 [M,256] ----
// Body = EXACT R1 form (best measured, reproduced twice at 466). block: 256 rows x
// 64 cols; wave: 64 rows (4 mt) x 64 cols (4 nt). C = ah*bh + ah*bl per kc.
// LDS: Wh full-K (33.8 KB) + Wl half-K (17.4 KB) restaged mid-kernel -> 3 blocks/CU.
// NEW: XCD-pinned dispatch. Old grid (c*196+r) put each A-panel's 4 col-blocks on
// 2 XCDs (196 = 4 mod 8) -> A fetched 2x from HBM. Pin all 4 to one XCD (b&7):
// A HBM traffic 51.2 -> 25.6 MB per GEMM. 16 dummy blocks uniform-exit.

#define GEMM_RB 196  // cdiv(50000,256)
#define GEMM_GRID (((GEMM_RB + 7) / 8) * 32)  // 25 q * 8 xcd * 4 c = 800

__global__ __launch_bounds__(256) void k_gemm_mfma(const unsigned short* __restrict__ Ah,
                                                   const unsigned short* __restrict__ Wth,
                                                   const unsigned short* __restrict__ Wtl,
                                                   unsigned short* __restrict__ C, int M) {
    __shared__ unsigned short Wh[64][264];  // full K, pad 8 -> 2-way (free)
    __shared__ unsigned short Wl[64][136];  // half K, pad 8
    int xcd = blockIdx.x & 7;
    int s5 = blockIdx.x >> 3;
    int colblk = s5 & 3;
    int rowblk = (s5 >> 2) * 8 + xcd;
    if (rowblk >= GEMM_RB) return;  // uniform early-exit (16 dummy blocks)
    int c0 = colblk * 64;
    int m0 = rowblk * 256;
    int t = threadIdx.x;
    int sr = t >> 2;

    {   // stage Wh (full 256 k) + Wl first half (k 0..127)
        int hk0 = (t & 3) * 64;
        const unsigned short* gh = Wth + (size_t)(c0 + sr) * 256 + hk0;
        unsigned short* lh = &Wh[sr][hk0];
#pragma unroll
        for (int i = 0; i < 8; ++i)
            *(uint4*)(lh + i * 8) = *(const uint4*)(gh + i * 8);
        int lk0 = (t & 3) * 32;
        const unsigned short* gl = Wtl + (size_t)(c0 + sr) * 256 + lk0;
        unsigned short* ll = &Wl[sr][lk0];
#pragma unroll
        for (int i = 0; i < 4; ++i)
            *(uint4*)(ll + i * 8) = *(const uint4*)(gl + i * 8);
    }
    __syncthreads();

    int lane = t & 63, wave = t >> 6;
    int quad = lane >> 4, l16 = lane & 15;

    const unsigned short* aph[4];
#pragma unroll
    for (int mt = 0; mt < 4; ++mt) {
        int m = m0 + wave * 64 + mt * 16 + l16;
        if (m >= M) m = M - 1;  // clamp loads; stores guarded
        aph[mt] = Ah + (size_t)m * 256 + quad * 8;
    }

    f32x4 acc[4][4];
#pragma unroll
    for (int i = 0; i < 4; ++i)
#pragma unroll
        for (int j = 0; j < 4; ++j) acc[i][j] = (f32x4){0.f, 0.f, 0.f, 0.f};

#pragma unroll 2
    for (int kc = 0; kc < 4; ++kc) {
        int ko = kc * 32;
        bf16x8 ahf[4];
#pragma unroll
        for (int mt = 0; mt < 4; ++mt) ahf[mt] = *(const bf16x8*)(aph[mt] + ko);
#pragma unroll
        for (int nt = 0; nt < 4; ++nt) {
            bf16x8 bh = *(const bf16x8*)&Wh[nt * 16 + l16][ko + quad * 8];
            bf16x8 bl = *(const bf16x8*)&Wl[nt * 16 + l16][ko + quad * 8];
#pragma unroll
            for (int mt = 0; mt < 4; ++mt) {
                acc[mt][nt] = __builtin_amdgcn_mfma_f32_16x16x32_bf16(ahf[mt], bh, acc[mt][nt], 0, 0, 0);
                acc[mt][nt] = __builtin_amdgcn_mfma_f32_16x16x32_bf16(ahf[mt], bl, acc[mt][nt], 0, 0, 0);
            }
        }
    }

    __syncthreads();  // all reads of Wl half 1 done
    {   // restage Wl second half (k 128..255)
        int lk0 = (t & 3) * 32;
        const unsigned short* gl = Wtl + (size_t)(c0 + sr) * 256 + 128 + lk0;
        unsigned short* ll = &Wl[sr][lk0];
#pragma unroll
        for (int i = 0; i < 4; ++i)
            *(uint4*)(ll + i * 8) = *(const uint4*)(gl + i * 8);
    }
    __syncthreads();

#pragma unroll 2
    for (int kc = 4; kc < 8; ++kc) {
        int ko = kc * 32;
        int kol = ko - 128;
        bf16x8 ahf[4];
#pragma unroll
        for (int mt = 0; mt < 4; ++mt) ahf[mt] = *(const bf16x8*)(aph[mt] + ko);
#pragma unroll
        for (int nt = 0; nt < 4; ++nt) {
            bf16x8 bh = *(const bf16x8*)&Wh[nt * 16 + l16][ko + quad * 8];
            bf16x8 bl = *(const bf16x8*)&Wl[nt * 16 + l16][kol + quad * 8];
#pragma unroll
            for (int mt = 0; mt < 4; ++mt) {
                acc[mt][nt] = __builtin_amdgcn_mfma_f32_16x16x32_bf16(ahf[mt], bh, acc[mt][nt], 0, 0, 0);
                acc[mt][nt] = __builtin_amdgcn_mfma_f32_16x16x32_bf16(ahf[mt], bl, acc[mt][nt], 0, 0, 0);
            }
        }
    }

    // permuted store: per (mt,r) one ushort4 at phys cols c0 + l16*4 + {0..3}
#pragma unroll
    for (int mt = 0; mt < 4; ++mt) {
#pragma unroll
        for (int r = 0; r < 4; ++r) {
            int row = m0 + wave * 64 + mt * 16 + quad * 4 + r;
            if (row < M) {
                ushort4 sv;
                sv.x = f2bf(acc[mt][0][r]);
                sv.y = f2bf(acc[mt][1][r]);
                sv.z = f2bf(acc[mt][2][r]);
                sv.w = f2bf(acc[mt][3][r]);
                *(ushort4*)(C + (size_t)row * 256 + c0 + l16 * 4) = sv;
            }
        }
    }
}

// ---------------- aggregation dim=256 over (permuted) bf16 messages ----------------
// one block per 4 nodes, in-dispatch-order (preserves gather L2 locality —
// measured R1 vs R2). wave per node, half-wave per edge, 6 edges in flight.
// MODE 0: bias+relu -> bf16 store. MODE 1: fused [256,2] projection -> t2.

template <int MODE>
__global__ __launch_bounds__(256, 8) void k_agg256(const unsigned short* __restrict__ t,
                                                   const int* __restrict__ row_ptr,
                                                   const int2* __restrict__ eg,
                                                   const float* __restrict__ bp,
                                                   unsigned short* __restrict__ outh,
                                                   const float* __restrict__ w3p,
                                                   float* __restrict__ t2, int n) {
    int lane = threadIdx.x & 63;
    int wave = threadIdx.x >> 6;
    int node = blockIdx.x * 4 + wave;
    if (node >= n) return;
    int half = lane >> 5;
    int fl = lane & 31;
    int beg = row_ptr[node], end = row_ptr[node + 1];
    f32x2 acc2[4];
#pragma unroll
    for (int i = 0; i < 4; ++i) { acc2[i].x = 0.f; acc2[i].y = 0.f; }
    const unsigned short* tp = t + fl * 8;

    int e = beg + half;
    for (; e + 10 < end; e += 12) {
        int2 a0 = ldnt2(eg + e), a1 = ldnt2(eg + e + 2), a2 = ldnt2(eg + e + 4);
        int2 a3 = ldnt2(eg + e + 6), a4 = ldnt2(eg + e + 8), a5 = ldnt2(eg + e + 10);
        uint4 v0 = *(const uint4*)(tp + (size_t)a0.x * 256);
        uint4 v1 = *(const uint4*)(tp + (size_t)a1.x * 256);
        uint4 v2 = *(const uint4*)(tp + (size_t)a2.x * 256);
        uint4 v3 = *(const uint4*)(tp + (size_t)a3.x * 256);
        uint4 v4 = *(const uint4*)(tp + (size_t)a4.x * 256);
        uint4 v5 = *(const uint4*)(tp + (size_t)a5.x * 256);
        acc8p(acc2, v0, __int_as_float(a0.y));
        acc8p(acc2, v1, __int_as_float(a1.y));
        acc8p(acc2, v2, __int_as_float(a2.y));
        acc8p(acc2, v3, __int_as_float(a3.y));
        acc8p(acc2, v4, __int_as_float(a4.y));
        acc8p(acc2, v5, __int_as_float(a5.y));
    }
    for (; e + 6 < end; e += 8) {
        int2 a0 = ldnt2(eg + e), a1 = ldnt2(eg + e + 2);
        int2 a2 = ldnt2(eg + e + 4), a3 = ldnt2(eg + e + 6);
        uint4 v0 = *(const uint4*)(tp + (size_t)a0.x * 256);
        uint4 v1 = *(const uint4*)(tp + (size_t)a1.x * 256);
        uint4 v2 = *(const uint4*)(tp + (size_t)a2.x * 256);
        uint4 v3 = *(const uint4*)(tp + (size_t)a3.x * 256);
        acc8p(acc2, v0, __int_as_float(a0.y));
        acc8p(acc2, v1, __int_as_float(a1.y));
        acc8p(acc2, v2, __int_as_float(a2.y));
        acc8p(acc2, v3, __int_as_float(a3.y));
    }
    for (; e + 2 < end; e += 4) {
        int2 a0 = ldnt2(eg + e), a1 = ldnt2(eg + e + 2);
        uint4 v0 = *(const uint4*)(tp + (size_t)a0.x * 256);
        uint4 v1 = *(const uint4*)(tp + (size_t)a1.x * 256);
        acc8p(acc2, v0, __int_as_float(a0.y));
        acc8p(acc2, v1, __int_as_float(a1.y));
    }
    if (e < end) {
        int2 a0 = ldnt2(eg + e);
        uint4 v0 = *(const uint4*)(tp + (size_t)a0.x * 256);
        acc8p(acc2, v0, __int_as_float(a0.y));
    }

    float va[8];
#pragma unroll
    for (int i = 0; i < 4; ++i) { va[2 * i] = acc2[i].x; va[2 * i + 1] = acc2[i].y; }
#pragma unroll
    for (int i = 0; i < 8; ++i) va[i] += __shfl_xor(va[i], 32);

    if (MODE == 0) {
        if (half == 0) {
            float4 bA = *(const float4*)(bp + fl * 8);
            float4 bB = *(const float4*)(bp + fl * 8 + 4);
            float r0 = fmaxf(va[0] + bA.x, 0.f), r1 = fmaxf(va[1] + bA.y, 0.f);
            float r2 = fmaxf(va[2] + bA.z, 0.f), r3 = fmaxf(va[3] + bA.w, 0.f);
            float r4 = fmaxf(va[4] + bB.x, 0.f), r5 = fmaxf(va[5] + bB.y, 0.f);
            float r6 = fmaxf(va[6] + bB.z, 0.f), r7 = fmaxf(va[7] + bB.w, 0.f);
            u32x4 w;
            w.x = (unsigned)f2bf(r0) | ((unsigned)f2bf(r1) << 16);
            w.y = (unsigned)f2bf(r2) | ((unsigned)f2bf(r3) << 16);
            w.z = (unsigned)f2bf(r4) | ((unsigned)f2bf(r5) << 16);
            w.w = (unsigned)f2bf(r6) | ((unsigned)f2bf(r7) << 16);
            __builtin_nontemporal_store(w, (u32x4*)(outh + (size_t)node * 256 + fl * 8));
        }
    } else {
        float4 bA = *(const float4*)(bp + fl * 8);
        float4 bB = *(const float4*)(bp + fl * 8 + 4);
        float r0 = fmaxf(va[0] + bA.x, 0.f), r1 = fmaxf(va[1] + bA.y, 0.f);
        float r2 = fmaxf(va[2] + bA.z, 0.f), r3 = fmaxf(va[3] + bA.w, 0.f);
        float r4 = fmaxf(va[4] + bB.x, 0.f), r5 = fmaxf(va[5] + bB.y, 0.f);
        float r6 = fmaxf(va[6] + bB.z, 0.f), r7 = fmaxf(va[7] + bB.w, 0.f);
        const float* wp = w3p + fl * 16;
        float4 wA = *(const float4*)(wp + 0);
        float4 wB = *(const float4*)(wp + 4);
        float4 wC = *(const float4*)(wp + 8);
        float4 wD = *(const float4*)(wp + 12);
        float s0 = r0 * wA.x + r1 * wA.z + r2 * wB.x + r3 * wB.z +
                   r4 * wC.x + r5 * wC.z + r6 * wD.x + r7 * wD.z;
        float s1 = r0 * wA.y + r1 * wA.w + r2 * wB.y + r3 * wB.w +
                   r4 * wC.y + r5 * wC.w + r6 * wD.y + r7 * wD.w;
#pragma unroll
        for (int off = 16; off > 0; off >>= 1) {
            s0 += __shfl_xor(s0, off);
            s1 += __shfl_xor(s1, off);
        }
        if (lane == 0) {
            f32x2 o;
            o.x = s0;
            o.y = s1;
            __builtin_nontemporal_store(o, (f32x2*)(t2 + (size_t)node * 2));
        }
    }
}

// ---------------- final aggregation of 2-wide rows: 4 lanes per node ----------------

__global__ void k_agg2(const float* __restrict__ t2,
                       const int* __restrict__ row_ptr,
                       const int2* __restrict__ eg,
                       const float* __restrict__ b3,
                       float* __restrict__ out, int n) {
    int tid = blockIdx.x * 256 + threadIdx.x;
    int node = tid >> 2;
    int sub = tid & 3;
    if (node >= n) return;
    int beg = row_ptr[node], end = row_ptr[node + 1];
    float a0 = 0.f, a1 = 0.f;
    for (int e = beg + sub; e < end; e += 4) {
        int2 m = ldnt2(eg + e);
        float w = __int_as_float(m.y);
        float2 v = *(const float2*)(t2 + (size_t)m.x * 2);
        a0 += w * v.x;
        a1 += w * v.y;
    }
    a0 += __shfl_xor(a0, 1); a1 += __shfl_xor(a1, 1);
    a0 += __shfl_xor(a0, 2); a1 += __shfl_xor(a1, 2);
    if (sub == 0) {
        out[(size_t)node * 2 + 0] = a0 + b3[0];
        out[(size_t)node * 2 + 1] = a1 + b3[1];
    }
}

// ---------------- launch ----------------

extern "C" void kernel_launch(void* const* d_in, const int* in_sizes, int n_in,
                              void* d_out, int out_size, void* d_ws, size_t ws_size,
                              hipStream_t stream) {
    const int N = N_NODES, E = N_EDGES;
    const float* x  = (const float*)d_in[0];
    const int* ei   = (const int*)d_in[1];
    const int* esrc = ei;
    const int* edst = ei + E;
    const float* W0 = (const float*)d_in[2];
    const float* b0 = (const float*)d_in[3];
    const float* W1 = (const float*)d_in[4];
    const float* b1 = (const float*)d_in[5];
    const float* W2 = (const float*)d_in[6];
    const float* b2 = (const float*)d_in[7];
    const float* W3 = (const float*)d_in[8];
    const float* b3 = (const float*)d_in[9];
    float* out = (float*)d_out;

    // workspace carve (8B-aligned regions first)
    unsigned short* Ahh = (unsigned short*)d_ws;            // N*256 bf16 h
    unsigned short* Tb  = Ahh + (size_t)N * 256;            // N*256 bf16 messages
    unsigned short* Wth = Tb + (size_t)N * 256;             // 3 x 256*256
    unsigned short* Wtl = Wth + 3 * 65536;                  // 3 x 256*256
    int2*  eg     = (int2*)(Wtl + 3 * 65536);               // E+N interleaved edge recs
    float* t2     = (float*)(eg + (E + N));                 // N*2
    float* bpw    = t2 + (size_t)N * 2;                     // 768 bias-perm + 512 W3-perm
    float* dis    = bpw + 1280;                             // N
    int*   cnt    = (int*)(dis + N);                        // N
    int*   row_ptr= cnt + N;                                // N+1
    int*   pos    = row_ptr + (N + 1);                      // N
    int*   blk    = pos + N;                                // cdiv(N,1024)

    const int NB = cdiv(N, 1024);
    const long total4 = (long)N * 64;
    const int CA = cdiv((int)total4, 256);

    // front-end: memset, then merged count+prep, then scans, then fill
    hipMemsetAsync(cnt, 0, (size_t)N * sizeof(int), stream);
    k_init<<<CNT_B + 49 + CA, 256, 0, stream>>>(edst, cnt, E,
                                                W0, W1, W2, b0, b1, b2, W3,
                                                Wth, Wtl, bpw, x, Ahh, total4);
    k_scan1<<<NB, 256, 0, stream>>>(cnt, row_ptr, dis, blk, N);
    k_scan2<<<1, 256, 0, stream>>>(blk, row_ptr + N, NB);
    k_scan3<<<NB, 256, 0, stream>>>(row_ptr, pos, blk, N);
    k_fill<<<cdiv(E + N, 256), 256, 0, stream>>>(esrc, edst, pos, dis, eg, E, N);

    const int agrid = cdiv(N, 4);  // in-order dispatch: preserves gather locality

    // layer 0
    k_gemm_mfma<<<GEMM_GRID, 256, 0, stream>>>(Ahh, Wth, Wtl, Tb, N);
    k_agg256<0><<<agrid, 256, 0, stream>>>(Tb, row_ptr, eg, bpw, Ahh, nullptr, nullptr, N);
    // layer 1
    k_gemm_mfma<<<GEMM_GRID, 256, 0, stream>>>(Ahh, Wth + 65536, Wtl + 65536, Tb, N);
    k_agg256<0><<<agrid, 256, 0, stream>>>(Tb, row_ptr, eg, bpw + 256, Ahh, nullptr, nullptr, N);
    // layer 2 + fused [256,2] projection
    k_gemm_mfma<<<GEMM_GRID, 256, 0, stream>>>(Ahh, Wth + 2 * 65536, Wtl + 2 * 65536, Tb, N);
    k_agg256<1><<<agrid, 256, 0, stream>>>(Tb, row_ptr, eg, bpw + 512, nullptr, bpw + 768, t2, N);
    // layer 3 (no relu)
    k_agg2<<<cdiv(4 * N, 256), 256, 0, stream>>>(t2, row_ptr, eg, b3, out, N);
}